// Round 15
// baseline (14854.617 us; speedup 1.0000x reference)
//
#include <hip/hip_runtime.h>
#include <math.h>

// Grid-RNN (WhileOpGridLSTMNet): DEPTH=2, SRC=TRG=32, B=32, H=256
// out[d][i][j][c][b][h], c=0:HX, c=1:HY
#define SRCN 32
#define TRGN 32
#define BN   32
#define HN   256
#define BH   (BN*HN)          // 8192 floats per (cell,channel)
#define CELL (2*BH)           // 16384 floats per cell
#define DSZ  ((size_t)SRCN*TRGN*CELL) // floats per depth
#define NRB  8                // batch rows per block
#define NBS  4                // batch slices per (L,i) row
#define KQ   64               // K per quarter

__host__ __device__ __forceinline__ int ncd(int t) { // cells on diag t (0..62)
    int a = t + 1, b = 63 - t;
    int m = a < b ? a : b;
    return m < 32 ? m : 32;
}

// RELAXED RMW poll (r10-r14 validated): coherence-point read, no invalidate.
__device__ __forceinline__ void spinwait(int* p) {
    for (int n = 0; n < (1 << 20); ++n) {
        if (__hip_atomic_fetch_add(p, 0, __ATOMIC_RELAXED, __HIP_MEMORY_SCOPE_AGENT) > 0)
            return;
        __builtin_amdgcn_s_sleep(2);
    }
}
__device__ __forceinline__ float cldf(const float* p) {
    return __hip_atomic_load(p, __ATOMIC_RELAXED, __HIP_MEMORY_SCOPE_AGENT);
}
__device__ __forceinline__ void cstf(float* p, float v) {
    __hip_atomic_store(p, v, __ATOMIC_RELAXED, __HIP_MEMORY_SCOPE_AGENT);
}

// acc[b] += sum_{k in [kof,kof+KQ)} S[b][k] * wc[(k-kof)*HN]
// Software-pipelined double-buffered LDS reads (r14-validated).
__device__ __forceinline__ void gemm8q(float* acc, const float (*S)[HN], int kof,
                                       const float* __restrict__ wc)
{
    float4 A[NRB], B[NRB];
#pragma unroll
    for (int b = 0; b < NRB; ++b) A[b] = *(const float4*)&S[b][kof];
    for (int k = 0; k < KQ; k += 8) {
#pragma unroll
        for (int b = 0; b < NRB; ++b) B[b] = *(const float4*)&S[b][kof + k + 4];
        {
            float w0 = wc[(k+0)*HN], w1 = wc[(k+1)*HN];
            float w2 = wc[(k+2)*HN], w3 = wc[(k+3)*HN];
#pragma unroll
            for (int b = 0; b < NRB; ++b)
                acc[b] += A[b].x*w0 + A[b].y*w1 + A[b].z*w2 + A[b].w*w3;
        }
        if (k + 8 < KQ) {
#pragma unroll
            for (int b = 0; b < NRB; ++b) A[b] = *(const float4*)&S[b][kof + k + 8];
        }
        {
            float w0 = wc[(k+4)*HN], w1 = wc[(k+5)*HN];
            float w2 = wc[(k+6)*HN], w3 = wc[(k+7)*HN];
#pragma unroll
            for (int b = 0; b < NRB; ++b)
                acc[b] += B[b].x*w0 + B[b].y*w1 + B[b].z*w2 + B[b].w*w3;
        }
    }
}

// ---------------------------------------------------------------------------
// proj0 (proven): xp0[i]=source[i]@W0 ; yp0[j]=target[j]@W0   (into ws)
// ---------------------------------------------------------------------------
__global__ __launch_bounds__(256) void proj0_kernel(
    const float* __restrict__ src, const float* __restrict__ trg,
    const float* __restrict__ W0, float* __restrict__ Xp0, float* __restrict__ Yp0)
{
    __shared__ float xs[BH];
    int blk = blockIdx.x >> 2, tile = blockIdx.x & 3;
    const float* X; float* P;
    if (blk < SRCN) { X = src + blk * BH; P = Xp0 + blk * BH; }
    else            { X = trg + (blk - SRCN) * BH; P = Yp0 + (blk - SRCN) * BH; }
    int tid = threadIdx.x;
    { const float4* x4 = (const float4*)X; float4* s4 = (float4*)xs;
#pragma unroll
      for (int r = 0; r < 8; ++r) s4[tid + r * 256] = x4[tid + r * 256]; }
    __syncthreads();
    int h = tile * 64 + (tid & 63), bg = tid >> 6;
    float acc[8] = {0,0,0,0,0,0,0,0};
    for (int k = 0; k < HN; k += 4) {
        float w0 = W0[(k+0)*HN+h], w1 = W0[(k+1)*HN+h], w2 = W0[(k+2)*HN+h], w3 = W0[(k+3)*HN+h];
#pragma unroll
        for (int bb = 0; bb < 8; ++bb) {
            int b = bg * 8 + bb;
            float4 xv = *(const float4*)&xs[b * HN + k];
            acc[bb] += xv.x*w0 + xv.y*w1 + xv.z*w2 + xv.w*w3;
        }
    }
#pragma unroll
    for (int bb = 0; bb < 8; ++bb) P[(bg*8+bb)*HN + h] = acc[bb];
}

// ---------------------------------------------------------------------------
// chain6_kernel: r14 structure, 1024 threads = (h, K-quarter).
//   blocks   0..127: L0 (i=b>>2, bs=b&3): Uy + Ux + [post] yp1=HY0@W1
//   blocks 128..255: L1: Uy + W1x + Ux + [post] HY=tanh(yp1+temp)
// 4 waves/SIMD (was 2) fills VALU issue slots during memory stalls.
// Per-wave lane0 spins; relaxed-RMW polls / sc1 data / RELEASE flags.
// ---------------------------------------------------------------------------
__global__ __launch_bounds__(1024, 1) void chain6_kernel(
    const float* __restrict__ W, const float* __restrict__ U,
    const float* __restrict__ bias, float* __restrict__ out,
    const float* __restrict__ xp0, const float* __restrict__ yp0,
    int* __restrict__ flg)
{
    __shared__ __align__(16) float sPrev[NRB][HN];    // own HX[i][j-1]
    __shared__ __align__(16) float sAux [NRB][HN];    // L0: hy ; L1: HX0
    __shared__ __align__(16) float sUp  [NRB][HN];    // HX[i-1][j]
    __shared__ __align__(16) float redT [3][NRB][HN]; // temp partials q1..q3
    __shared__ __align__(16) float redX [3][NRB][HN]; // aX partials q1..q3

    const int bid = blockIdx.x;         // 0..255
    const int L   = bid >> 7;
    const int i   = (bid >> 2) & 31;
    const int bs  = bid & 3;
    const int r0  = bs * NRB;
    const int tid = threadIdx.x;        // 0..1023
    const int h   = tid & 255;
    const int kq  = tid >> 8;           // K-quarter 0..3
    const int kof = kq * KQ;
    const bool q0 = (kq == 0);
    const bool wl = ((tid & 63) == 0);  // wave leader

    int* fL0 = flg;                     // L0 main flags
    int* fP1 = flg + 4096;              // yp1 ready flags
    int* fL1 = flg + 8192;              // L1 main flags

    const float* UxB = U + (size_t)L * 131072 + (size_t)kof * HN + h;
    const float* UyB = UxB + 65536;
    const float* W1B = W + 65536 + (size_t)kof * HN + h;
    const float bv   = bias[L * HN + h];
    float* outL = out + (size_t)L * DSZ;

    sPrev[kq * 2][h]     = 0.f;
    sPrev[kq * 2 + 1][h] = 0.f;
    __syncthreads();

    for (int j = 0; j < TRGN; ++j) {
        const int cell = i * TRGN + j;
        const int fidx = cell * NBS + bs;
        float acc[NRB] = {0.f,0.f,0.f,0.f,0.f,0.f,0.f,0.f};

        if (L == 0) {
            // ====================== L0 body =======================
            if (j > 0) gemm8q(acc, sPrev, kof, UyB);
            if (i > 0) {
                if (wl) spinwait(&fL0[fidx - 32 * NBS]);
                __atomic_signal_fence(__ATOMIC_ACQUIRE);
                const float* up = outL + (size_t)(cell - 32) * CELL + (size_t)r0 * HN + h;
                sUp[kq * 2][h]     = cldf(up + (kq * 2) * HN);
                sUp[kq * 2 + 1][h] = cldf(up + (kq * 2 + 1) * HN);
                __syncthreads();
                gemm8q(acc, sUp, kof, UxB);
            }
            if (!q0) {
#pragma unroll
                for (int b = 0; b < NRB; ++b) redT[kq - 1][b][h] = acc[b];
            }
            __syncthreads();
            if (q0) {
                const float* xr = xp0 + (size_t)i * BH + (size_t)r0 * HN + h; // L1$-hot
                const float* yr = yp0 + (size_t)j * BH + (size_t)r0 * HN + h;
                float* ox = outL + (size_t)cell * CELL + (size_t)r0 * HN + h;
#pragma unroll
                for (int b = 0; b < NRB; ++b) {
                    float tp = acc[b] + redT[0][b][h] + redT[1][b][h]
                             + redT[2][b][h] + bv;
                    float hx = tanhf(xr[b * HN] + tp);
                    float hy = tanhf(yr[b * HN] + tp);
                    cstf(ox + b * HN, hx);
                    cstf(ox + BH + b * HN, hy);
                    sPrev[b][h] = hx;
                    sAux[b][h]  = hy;
                }
            }
            __syncthreads();   // stores drained + sPrev/sAux visible
            if (tid == 0)
                __hip_atomic_fetch_add(&fL0[fidx], 1, __ATOMIC_RELEASE, __HIP_MEMORY_SCOPE_AGENT);

            // ---- post: yp1 = HY0 @ W1 (off L1's HX critical path) ----
            float aY[NRB] = {0.f,0.f,0.f,0.f,0.f,0.f,0.f,0.f};
            gemm8q(aY, sAux, kof, W1B);
            if (!q0) {
#pragma unroll
                for (int b = 0; b < NRB; ++b) redT[kq - 1][b][h] = aY[b];
            }
            __syncthreads();
            if (q0) {
                float* yd = out + DSZ + (size_t)cell * CELL + BH + (size_t)r0 * HN + h;
#pragma unroll
                for (int b = 0; b < NRB; ++b)
                    cstf(yd + b * HN, aY[b] + redT[0][b][h] + redT[1][b][h]
                                    + redT[2][b][h]);
            }
            __syncthreads();
            if (tid == 0)
                __hip_atomic_fetch_add(&fP1[fidx], 1, __ATOMIC_RELEASE, __HIP_MEMORY_SCOPE_AGENT);
        } else {
            // ====================== L1 body =======================
            if (wl) spinwait(&fL0[fidx]);            // long-set in steady state
            __atomic_signal_fence(__ATOMIC_ACQUIRE);
            {   // issue sAux stage loads; Uy GEMM below hides their latency
                const float* x0 = out + (size_t)cell * CELL + (size_t)r0 * HN + h;
                sAux[kq * 2][h]     = cldf(x0 + (kq * 2) * HN);
                sAux[kq * 2 + 1][h] = cldf(x0 + (kq * 2 + 1) * HN);
            }
            if (j > 0) gemm8q(acc, sPrev, kof, UyB); // independent of sAux
            __syncthreads();
            float aX[NRB] = {0.f,0.f,0.f,0.f,0.f,0.f,0.f,0.f};
            gemm8q(aX, sAux, kof, W1B);              // xp1 = HX0 @ W1
            if (i > 0) {
                if (wl) spinwait(&fL1[fidx - 32 * NBS]);
                __atomic_signal_fence(__ATOMIC_ACQUIRE);
                const float* up = outL + (size_t)(cell - 32) * CELL + (size_t)r0 * HN + h;
                sUp[kq * 2][h]     = cldf(up + (kq * 2) * HN);
                sUp[kq * 2 + 1][h] = cldf(up + (kq * 2 + 1) * HN);
                __syncthreads();
                gemm8q(acc, sUp, kof, UxB);
            }
            if (!q0) {
#pragma unroll
                for (int b = 0; b < NRB; ++b) {
                    redT[kq - 1][b][h] = acc[b];
                    redX[kq - 1][b][h] = aX[b];
                }
            }
            __syncthreads();
            float temp[NRB];
            if (q0) {
                float* ox = outL + (size_t)cell * CELL + (size_t)r0 * HN + h;
#pragma unroll
                for (int b = 0; b < NRB; ++b) {
                    float tp = acc[b] + redT[0][b][h] + redT[1][b][h]
                             + redT[2][b][h] + bv;
                    temp[b] = tp;
                    float hx = tanhf(aX[b] + redX[0][b][h] + redX[1][b][h]
                                   + redX[2][b][h] + tp);
                    cstf(ox + b * HN, hx);
                    sPrev[b][h] = hx;
                }
            }
            __syncthreads();   // stores drained + sPrev visible
            if (tid == 0)
                __hip_atomic_fetch_add(&fL1[fidx], 1, __ATOMIC_RELEASE, __HIP_MEMORY_SCOPE_AGENT);

            // ---- post: HY = tanh(yp1 + temp); fP1 long-set ----
            if (q0) {
                if (wl) spinwait(&fP1[fidx]);
                __atomic_signal_fence(__ATOMIC_ACQUIRE);
                float* oy = outL + (size_t)cell * CELL + BH + (size_t)r0 * HN + h;
#pragma unroll
                for (int b = 0; b < NRB; ++b) {
                    float yp = cldf(oy + b * HN);     // same-thread read->overwrite
                    oy[b * HN] = tanhf(yp + temp[b]); // plain store, no consumer
                }
            }
        }
    }
}

// ===========================================================================
// Fallback (round-1 ladder, proven): used only if ws_size is too small.
// ===========================================================================
__global__ __launch_bounds__(256) void proj1_kernel(
    float* __restrict__ out, const float* __restrict__ W1)
{
    __shared__ float hxs[BH];
    __shared__ float hys[BH];
    int cell = blockIdx.x >> 2, tile = blockIdx.x & 3;
    const float* hx0 = out + (size_t)cell * CELL;
    const float* hy0 = hx0 + BH;
    float* xp1 = out + DSZ + (size_t)cell * CELL;
    float* yp1 = xp1 + BH;
    int tid = threadIdx.x;
    { const float4* a4 = (const float4*)hx0; const float4* b4 = (const float4*)hy0;
      float4* sa = (float4*)hxs; float4* sb = (float4*)hys;
#pragma unroll
      for (int r = 0; r < 8; ++r) { sa[tid+r*256] = a4[tid+r*256]; sb[tid+r*256] = b4[tid+r*256]; } }
    __syncthreads();
    int h = tile * 64 + (tid & 63), bg = tid >> 6;
    float ax[8] = {0,0,0,0,0,0,0,0}, ay[8] = {0,0,0,0,0,0,0,0};
    for (int k = 0; k < HN; k += 4) {
        float w0 = W1[(k+0)*HN+h], w1 = W1[(k+1)*HN+h], w2 = W1[(k+2)*HN+h], w3 = W1[(k+3)*HN+h];
#pragma unroll
        for (int bb = 0; bb < 8; ++bb) {
            int b = bg * 8 + bb;
            float4 xv = *(const float4*)&hxs[b*HN+k];
            float4 yv = *(const float4*)&hys[b*HN+k];
            ax[bb] += xv.x*w0 + xv.y*w1 + xv.z*w2 + xv.w*w3;
            ay[bb] += yv.x*w0 + yv.y*w1 + yv.z*w2 + yv.w*w3;
        }
    }
#pragma unroll
    for (int bb = 0; bb < 8; ++bb) {
        int b = bg * 8 + bb;
        xp1[b*HN+h] = ax[bb]; yp1[b*HN+h] = ay[bb];
    }
}

__global__ __launch_bounds__(256) void diag_kernel(
    float* out, const float* __restrict__ U, const float* __restrict__ bias,
    const float* __restrict__ Xp0, const float* __restrict__ Yp0, int d, int t)
{
    __shared__ float sxs[BH];
    __shared__ float phs[BH];
    int c = blockIdx.x >> 2, tile = blockIdx.x & 3;
    int i0 = t - (TRGN - 1); if (i0 < 0) i0 = 0;
    int i = i0 + c, j = t - i;
    const float* Ux = U + d * (2 * HN * HN);
    const float* Uy = Ux + HN * HN;
    float* outD = out + (size_t)d * DSZ;
    const float* sx = (i > 0) ? outD + (size_t)((i-1)*TRGN + j) * CELL : nullptr;
    const float* ph = (j > 0) ? outD + (size_t)(i*TRGN + (j-1)) * CELL : nullptr;
    float* oHX = outD + (size_t)(i*TRGN + j) * CELL;
    float* oHY = oHX + BH;
    const float* xp = d ? oHX : (Xp0 + i * BH);
    const float* yp = d ? oHY : (Yp0 + j * BH);
    const float* bd = bias + d * HN;
    int tid = threadIdx.x;
    { const float4* s4 = (const float4*)sx; const float4* p4 = (const float4*)ph;
      float4* d1 = (float4*)sxs; float4* d2 = (float4*)phs;
      float4 z = make_float4(0.f,0.f,0.f,0.f);
#pragma unroll
      for (int r = 0; r < 8; ++r) { int idx = tid + r*256; d1[idx] = sx ? s4[idx] : z; d2[idx] = ph ? p4[idx] : z; } }
    __syncthreads();
    int h = tile * 64 + (tid & 63), bg = tid >> 6;
    float acc[8] = {0,0,0,0,0,0,0,0};
    for (int k = 0; k < HN; k += 4) {
        float ux0 = Ux[(k+0)*HN+h], ux1 = Ux[(k+1)*HN+h], ux2 = Ux[(k+2)*HN+h], ux3 = Ux[(k+3)*HN+h];
        float uy0 = Uy[(k+0)*HN+h], uy1 = Uy[(k+1)*HN+h], uy2 = Uy[(k+2)*HN+h], uy3 = Uy[(k+3)*HN+h];
#pragma unroll
        for (int bb = 0; bb < 8; ++bb) {
            int b = bg * 8 + bb;
            float4 sv = *(const float4*)&sxs[b*HN+k];
            float4 pv = *(const float4*)&phs[b*HN+k];
            acc[bb] += sv.x*ux0 + sv.y*ux1 + sv.z*ux2 + sv.w*ux3
                     + pv.x*uy0 + pv.y*uy1 + pv.z*uy2 + pv.w*uy3;
        }
    }
    float bv = bd[h];
#pragma unroll
    for (int bb = 0; bb < 8; ++bb) {
        int b = bg * 8 + bb;
        float temp = acc[bb] + bv;
        oHX[b*HN+h] = tanhf(xp[b*HN+h] + temp);
        oHY[b*HN+h] = tanhf(yp[b*HN+h] + temp);
    }
}

// ===========================================================================
extern "C" void kernel_launch(void* const* d_in, const int* in_sizes, int n_in,
                              void* d_out, int out_size, void* d_ws, size_t ws_size,
                              hipStream_t stream)
{
    const float* source = (const float*)d_in[0];
    const float* target = (const float*)d_in[1];
    const float* W      = (const float*)d_in[2]; // [2][256][256]
    const float* U      = (const float*)d_in[3]; // [2][512][256]
    const float* bias   = (const float*)d_in[4]; // [2][1][256]
    float* out = (float*)d_out;

    // ws layout: xp0 [1MB] | yp0 [1MB] | flags [48KB: L0, p1y, L1]
    const size_t need = 2u * 1024 * 1024 + 49152;
    if (d_ws != nullptr && ws_size >= need) {
        float* xp0 = (float*)d_ws;
        float* yp0 = xp0 + 32 * BH;
        int*   flg = (int*)(yp0 + 32 * BH);
        hipMemsetAsync(flg, 0, 3 * 4096 * sizeof(int), stream);
        proj0_kernel<<<dim3(64 * 4), dim3(256), 0, stream>>>(source, target, W, xp0, yp0);
        chain6_kernel<<<dim3(256), dim3(1024), 0, stream>>>(
            W, U, bias, out, xp0, yp0, flg);
    } else {
        // Proven round-1 ladder (scratch aliased into out[1] region; safe
        // because proj1 runs only after ALL layer-0 diagonals).
        float* Xp0 = out + DSZ;
        float* Yp0 = Xp0 + SRCN * BH;
        proj0_kernel<<<dim3(64 * 4), dim3(256), 0, stream>>>(source, target, W, Xp0, Yp0);
        for (int t = 0; t < SRCN + TRGN - 1; ++t) {
            int nc = ncd(t);
            diag_kernel<<<dim3(nc * 4), dim3(256), 0, stream>>>(out, U, bias, Xp0, Yp0, 0, t);
        }
        proj1_kernel<<<dim3(1024 * 4), dim3(256), 0, stream>>>(out, W + HN * HN);
        for (int t = 0; t < SRCN + TRGN - 1; ++t) {
            int nc = ncd(t);
            diag_kernel<<<dim3(nc * 4), dim3(256), 0, stream>>>(out, U, bias, nullptr, nullptr, 1, t);
        }
    }
}

// Round 16
// 1415.175 us; speedup vs baseline: 10.4967x; 10.4967x over previous
//
#include <hip/hip_runtime.h>
#include <math.h>

// Grid-RNN (WhileOpGridLSTMNet): DEPTH=2, SRC=TRG=32, B=32, H=256
// out[d][i][j][c][b][h], c=0:HX, c=1:HY
#define SRCN 32
#define TRGN 32
#define BN   32
#define HN   256
#define BH   (BN*HN)          // 8192 floats per (cell,channel)
#define CELL (2*BH)           // 16384 floats per cell
#define DSZ  ((size_t)SRCN*TRGN*CELL) // floats per depth
#define NRB  8                // batch rows per block
#define NBS  4                // batch slices per (L,i) row

__host__ __device__ __forceinline__ int ncd(int t) { // cells on diag t (0..62)
    int a = t + 1, b = 63 - t;
    int m = a < b ? a : b;
    return m < 32 ? m : 32;
}

// RELAXED RMW poll (r10-r14 validated at <=2048 pollers; r15 showed 4096
// pollers collapse the L3 atomic path to HBM). Coherence-point read, no
// cache invalidate. Bounded: never hangs the harness.
__device__ __forceinline__ void spinwait(int* p) {
    for (int n = 0; n < (1 << 20); ++n) {
        if (__hip_atomic_fetch_add(p, 0, __ATOMIC_RELAXED, __HIP_MEMORY_SCOPE_AGENT) > 0)
            return;
        __builtin_amdgcn_s_sleep(2);
    }
}
__device__ __forceinline__ float cldf(const float* p) {
    return __hip_atomic_load(p, __ATOMIC_RELAXED, __HIP_MEMORY_SCOPE_AGENT);
}
__device__ __forceinline__ void cstf(float* p, float v) {
    __hip_atomic_store(p, v, __ATOMIC_RELAXED, __HIP_MEMORY_SCOPE_AGENT);
}

// acc[b] += sum_{k in [kof,kof+128)} S[b][k] * wc[(k-kof)*HN]
// Software-pipelined double-buffered LDS reads (r14-validated).
__device__ __forceinline__ void gemm8p(float* acc, const float (*S)[HN], int kof,
                                       const float* __restrict__ wc)
{
    float4 A[NRB], B[NRB];
#pragma unroll
    for (int b = 0; b < NRB; ++b) A[b] = *(const float4*)&S[b][kof];
    for (int k = 0; k < 128; k += 8) {
#pragma unroll
        for (int b = 0; b < NRB; ++b) B[b] = *(const float4*)&S[b][kof + k + 4];
        {
            float w0 = wc[(k+0)*HN], w1 = wc[(k+1)*HN];
            float w2 = wc[(k+2)*HN], w3 = wc[(k+3)*HN];
#pragma unroll
            for (int b = 0; b < NRB; ++b)
                acc[b] += A[b].x*w0 + A[b].y*w1 + A[b].z*w2 + A[b].w*w3;
        }
        if (k + 8 < 128) {
#pragma unroll
            for (int b = 0; b < NRB; ++b) A[b] = *(const float4*)&S[b][kof + k + 8];
        }
        {
            float w0 = wc[(k+4)*HN], w1 = wc[(k+5)*HN];
            float w2 = wc[(k+6)*HN], w3 = wc[(k+7)*HN];
#pragma unroll
            for (int b = 0; b < NRB; ++b)
                acc[b] += B[b].x*w0 + B[b].y*w1 + B[b].z*w2 + B[b].w*w3;
        }
    }
}

// ---------------------------------------------------------------------------
// proj0 (proven): xp0[i]=source[i]@W0 ; yp0[j]=target[j]@W0   (into ws)
// ---------------------------------------------------------------------------
__global__ __launch_bounds__(256) void proj0_kernel(
    const float* __restrict__ src, const float* __restrict__ trg,
    const float* __restrict__ W0, float* __restrict__ Xp0, float* __restrict__ Yp0)
{
    __shared__ float xs[BH];
    int blk = blockIdx.x >> 2, tile = blockIdx.x & 3;
    const float* X; float* P;
    if (blk < SRCN) { X = src + blk * BH; P = Xp0 + blk * BH; }
    else            { X = trg + (blk - SRCN) * BH; P = Yp0 + (blk - SRCN) * BH; }
    int tid = threadIdx.x;
    { const float4* x4 = (const float4*)X; float4* s4 = (float4*)xs;
#pragma unroll
      for (int r = 0; r < 8; ++r) s4[tid + r * 256] = x4[tid + r * 256]; }
    __syncthreads();
    int h = tile * 64 + (tid & 63), bg = tid >> 6;
    float acc[8] = {0,0,0,0,0,0,0,0};
    for (int k = 0; k < HN; k += 4) {
        float w0 = W0[(k+0)*HN+h], w1 = W0[(k+1)*HN+h], w2 = W0[(k+2)*HN+h], w3 = W0[(k+3)*HN+h];
#pragma unroll
        for (int bb = 0; bb < 8; ++bb) {
            int b = bg * 8 + bb;
            float4 xv = *(const float4*)&xs[b * HN + k];
            acc[bb] += xv.x*w0 + xv.y*w1 + xv.z*w2 + xv.w*w3;
        }
    }
#pragma unroll
    for (int bb = 0; bb < 8; ++bb) P[(bg*8+bb)*HN + h] = acc[bb];
}

// ---------------------------------------------------------------------------
// chain7_kernel: r14 structure EXACTLY (1469us proven), plus an XCD-aware
// blockIdx remap: the 4 bs-slices of each (L,i) are placed on ONE XCD
// (XCD ~ blockIdx%8 round-robin) so they share the L2-resident weight
// stream -> 4x less L2 weight pressure per XCD. Correctness is flag-based
// and independent of the mapping.
//   L0 body: Uy + Ux + [post] yp1=HY0@W1
//   L1 body: Uy + W1x + Ux + [post] HY=tanh(yp1+temp)
// ---------------------------------------------------------------------------
__global__ __launch_bounds__(512, 1) void chain7_kernel(
    const float* __restrict__ W, const float* __restrict__ U,
    const float* __restrict__ bias, float* __restrict__ out,
    const float* __restrict__ xp0, const float* __restrict__ yp0,
    int* __restrict__ flg)
{
    __shared__ __align__(16) float sPrev[NRB][HN]; // own HX[i][j-1]
    __shared__ __align__(16) float sAux [NRB][HN]; // L0: hy ; L1: staged HX0
    __shared__ __align__(16) float sUp  [NRB][HN]; // HX[i-1][j]
    __shared__ __align__(16) float redT [NRB][HN]; // temp / aY reduce
    __shared__ __align__(16) float redX [NRB][HN]; // L1: aX reduce

    const int bid = blockIdx.x;         // 0..255
    // XCD-aware remap: idx=(L*32+i) in 0..63 -> xcd=idx%8, grp=idx/8.
    // bid = xcd + 8*(grp*4 + bs)  =>  4 bs-blocks of (L,i) share one XCD.
    const int xcd = bid & 7;
    const int t8  = bid >> 3;
    const int grp = t8 >> 2;
    const int bs  = t8 & 3;
    const int idx = grp * 8 + xcd;      // 0..63
    const int L   = idx >> 5;
    const int i   = idx & 31;
    const int r0  = bs * NRB;
    const int tid = threadIdx.x;        // 0..511
    const int h   = tid & 255;
    const int kh  = tid >> 8;           // K-half
    const int kof = kh * 128;
    const bool k0 = (kh == 0);
    const bool wl = ((tid & 63) == 0);  // wave leader

    int* fL0 = flg;                     // L0 main flags
    int* fP1 = flg + 4096;              // yp1 ready flags
    int* fL1 = flg + 8192;              // L1 main flags

    const float* UxB = U + (size_t)L * 131072 + (size_t)kof * HN + h;
    const float* UyB = UxB + 65536;
    const float* W1B = W + 65536 + (size_t)kof * HN + h;
    const float bv   = bias[L * HN + h];
    float* outL = out + (size_t)L * DSZ;

#pragma unroll
    for (int bb = 0; bb < 4; ++bb) sPrev[kh * 4 + bb][h] = 0.f;
    __syncthreads();

    for (int j = 0; j < TRGN; ++j) {
        const int cell = i * TRGN + j;
        const int fidx = cell * NBS + bs;
        float acc[NRB] = {0.f,0.f,0.f,0.f,0.f,0.f,0.f,0.f};

        if (L == 0) {
            // ====================== L0 body =======================
            float xin[NRB], yin[NRB];
            if (k0) {
                const float* xr = xp0 + (size_t)i * BH + (size_t)r0 * HN + h;
                const float* yr = yp0 + (size_t)j * BH + (size_t)r0 * HN + h;
#pragma unroll
                for (int b = 0; b < NRB; ++b) { xin[b] = xr[b*HN]; yin[b] = yr[b*HN]; }
            }
            if (j > 0) gemm8p(acc, sPrev, kof, UyB);
            if (i > 0) {
                if (wl) spinwait(&fL0[fidx - 32 * NBS]);
                __atomic_signal_fence(__ATOMIC_ACQUIRE);
                const float* up = outL + (size_t)(cell - 32) * CELL + (size_t)r0 * HN + h;
#pragma unroll
                for (int bb = 0; bb < 4; ++bb) { int b = kh*4+bb; sUp[b][h] = cldf(up + b*HN); }
                __syncthreads();
                gemm8p(acc, sUp, kof, UxB);
            }
            if (kh == 1) {
#pragma unroll
                for (int b = 0; b < NRB; ++b) redT[b][h] = acc[b];
            }
            __syncthreads();
            if (k0) {
                float* ox = outL + (size_t)cell * CELL + (size_t)r0 * HN + h;
#pragma unroll
                for (int b = 0; b < NRB; ++b) {
                    float tp = acc[b] + redT[b][h] + bv;
                    float hx = tanhf(xin[b] + tp);
                    float hy = tanhf(yin[b] + tp);
                    cstf(ox + b * HN, hx);
                    cstf(ox + BH + b * HN, hy);
                    sPrev[b][h] = hx;
                    sAux[b][h]  = hy;
                }
            }
            __syncthreads();   // stores drained + sPrev/sAux visible
            if (tid == 0)
                __hip_atomic_fetch_add(&fL0[fidx], 1, __ATOMIC_RELEASE, __HIP_MEMORY_SCOPE_AGENT);

            // ---- post: yp1 = HY0 @ W1 (off L1's HX critical path) ----
            float aY[NRB] = {0.f,0.f,0.f,0.f,0.f,0.f,0.f,0.f};
            gemm8p(aY, sAux, kof, W1B);
            if (kh == 1) {
#pragma unroll
                for (int b = 0; b < NRB; ++b) redT[b][h] = aY[b];
            }
            __syncthreads();
            if (k0) {
                float* yd = out + DSZ + (size_t)cell * CELL + BH + (size_t)r0 * HN + h;
#pragma unroll
                for (int b = 0; b < NRB; ++b) cstf(yd + b * HN, aY[b] + redT[b][h]);
            }
            __syncthreads();
            if (tid == 0)
                __hip_atomic_fetch_add(&fP1[fidx], 1, __ATOMIC_RELEASE, __HIP_MEMORY_SCOPE_AGENT);
        } else {
            // ====================== L1 body =======================
            if (wl) spinwait(&fL0[fidx]);            // long-set in steady state
            __atomic_signal_fence(__ATOMIC_ACQUIRE);
            {
                const float* x0 = out + (size_t)cell * CELL + (size_t)r0 * HN + h;
#pragma unroll
                for (int bb = 0; bb < 4; ++bb) { int b = kh*4+bb; sAux[b][h] = cldf(x0 + b*HN); }
            }
            if (j > 0) gemm8p(acc, sPrev, kof, UyB); // independent of sAux
            __syncthreads();
            float aX[NRB] = {0.f,0.f,0.f,0.f,0.f,0.f,0.f,0.f};
            gemm8p(aX, sAux, kof, W1B);              // xp1 = HX0 @ W1
            if (i > 0) {
                if (wl) spinwait(&fL1[fidx - 32 * NBS]);
                __atomic_signal_fence(__ATOMIC_ACQUIRE);
                const float* up = outL + (size_t)(cell - 32) * CELL + (size_t)r0 * HN + h;
#pragma unroll
                for (int bb = 0; bb < 4; ++bb) { int b = kh*4+bb; sUp[b][h] = cldf(up + b*HN); }
                __syncthreads();
                gemm8p(acc, sUp, kof, UxB);
            }
            if (kh == 1) {
#pragma unroll
                for (int b = 0; b < NRB; ++b) { redT[b][h] = acc[b]; redX[b][h] = aX[b]; }
            }
            __syncthreads();
            float temp[NRB];
            if (k0) {
                float* ox = outL + (size_t)cell * CELL + (size_t)r0 * HN + h;
#pragma unroll
                for (int b = 0; b < NRB; ++b) {
                    float tp = acc[b] + redT[b][h] + bv;
                    temp[b] = tp;
                    float hx = tanhf(aX[b] + redX[b][h] + tp);
                    cstf(ox + b * HN, hx);
                    sPrev[b][h] = hx;
                }
            }
            __syncthreads();   // stores drained + sPrev visible
            if (tid == 0)
                __hip_atomic_fetch_add(&fL1[fidx], 1, __ATOMIC_RELEASE, __HIP_MEMORY_SCOPE_AGENT);

            // ---- post: HY = tanh(yp1 + temp); fP1 long-set ----
            if (k0) {
                if (wl) spinwait(&fP1[fidx]);
                __atomic_signal_fence(__ATOMIC_ACQUIRE);
                float* oy = outL + (size_t)cell * CELL + BH + (size_t)r0 * HN + h;
#pragma unroll
                for (int b = 0; b < NRB; ++b) {
                    float yp = cldf(oy + b * HN);    // same-thread read->overwrite
                    oy[b * HN] = tanhf(yp + temp[b]); // plain store, no consumer
                }
            }
        }
    }
}

// ===========================================================================
// Fallback (round-1 ladder, proven): used only if ws_size is too small.
// ===========================================================================
__global__ __launch_bounds__(256) void proj1_kernel(
    float* __restrict__ out, const float* __restrict__ W1)
{
    __shared__ float hxs[BH];
    __shared__ float hys[BH];
    int cell = blockIdx.x >> 2, tile = blockIdx.x & 3;
    const float* hx0 = out + (size_t)cell * CELL;
    const float* hy0 = hx0 + BH;
    float* xp1 = out + DSZ + (size_t)cell * CELL;
    float* yp1 = xp1 + BH;
    int tid = threadIdx.x;
    { const float4* a4 = (const float4*)hx0; const float4* b4 = (const float4*)hy0;
      float4* sa = (float4*)hxs; float4* sb = (float4*)hys;
#pragma unroll
      for (int r = 0; r < 8; ++r) { sa[tid+r*256] = a4[tid+r*256]; sb[tid+r*256] = b4[tid+r*256]; } }
    __syncthreads();
    int h = tile * 64 + (tid & 63), bg = tid >> 6;
    float ax[8] = {0,0,0,0,0,0,0,0}, ay[8] = {0,0,0,0,0,0,0,0};
    for (int k = 0; k < HN; k += 4) {
        float w0 = W1[(k+0)*HN+h], w1 = W1[(k+1)*HN+h], w2 = W1[(k+2)*HN+h], w3 = W1[(k+3)*HN+h];
#pragma unroll
        for (int bb = 0; bb < 8; ++bb) {
            int b = bg * 8 + bb;
            float4 xv = *(const float4*)&hxs[b*HN+k];
            float4 yv = *(const float4*)&hys[b*HN+k];
            ax[bb] += xv.x*w0 + xv.y*w1 + xv.z*w2 + xv.w*w3;
            ay[bb] += yv.x*w0 + yv.y*w1 + yv.z*w2 + yv.w*w3;
        }
    }
#pragma unroll
    for (int bb = 0; bb < 8; ++bb) {
        int b = bg * 8 + bb;
        xp1[b*HN+h] = ax[bb]; yp1[b*HN+h] = ay[bb];
    }
}

__global__ __launch_bounds__(256) void diag_kernel(
    float* out, const float* __restrict__ U, const float* __restrict__ bias,
    const float* __restrict__ Xp0, const float* __restrict__ Yp0, int d, int t)
{
    __shared__ float sxs[BH];
    __shared__ float phs[BH];
    int c = blockIdx.x >> 2, tile = blockIdx.x & 3;
    int i0 = t - (TRGN - 1); if (i0 < 0) i0 = 0;
    int i = i0 + c, j = t - i;
    const float* Ux = U + d * (2 * HN * HN);
    const float* Uy = Ux + HN * HN;
    float* outD = out + (size_t)d * DSZ;
    const float* sx = (i > 0) ? outD + (size_t)((i-1)*TRGN + j) * CELL : nullptr;
    const float* ph = (j > 0) ? outD + (size_t)(i*TRGN + (j-1)) * CELL : nullptr;
    float* oHX = outD + (size_t)(i*TRGN + j) * CELL;
    float* oHY = oHX + BH;
    const float* xp = d ? oHX : (Xp0 + i * BH);
    const float* yp = d ? oHY : (Yp0 + j * BH);
    const float* bd = bias + d * HN;
    int tid = threadIdx.x;
    { const float4* s4 = (const float4*)sx; const float4* p4 = (const float4*)ph;
      float4* d1 = (float4*)sxs; float4* d2 = (float4*)phs;
      float4 z = make_float4(0.f,0.f,0.f,0.f);
#pragma unroll
      for (int r = 0; r < 8; ++r) { int idx = tid + r*256; d1[idx] = sx ? s4[idx] : z; d2[idx] = ph ? p4[idx] : z; } }
    __syncthreads();
    int h = tile * 64 + (tid & 63), bg = tid >> 6;
    float acc[8] = {0,0,0,0,0,0,0,0};
    for (int k = 0; k < HN; k += 4) {
        float ux0 = Ux[(k+0)*HN+h], ux1 = Ux[(k+1)*HN+h], ux2 = Ux[(k+2)*HN+h], ux3 = Ux[(k+3)*HN+h];
        float uy0 = Uy[(k+0)*HN+h], uy1 = Uy[(k+1)*HN+h], uy2 = Uy[(k+2)*HN+h], uy3 = Uy[(k+3)*HN+h];
#pragma unroll
        for (int bb = 0; bb < 8; ++bb) {
            int b = bg * 8 + bb;
            float4 sv = *(const float4*)&sxs[b*HN+k];
            float4 pv = *(const float4*)&phs[b*HN+k];
            acc[bb] += sv.x*ux0 + sv.y*ux1 + sv.z*ux2 + sv.w*ux3
                     + pv.x*uy0 + pv.y*uy1 + pv.z*uy2 + pv.w*uy3;
        }
    }
    float bv = bd[h];
#pragma unroll
    for (int bb = 0; bb < 8; ++bb) {
        int b = bg * 8 + bb;
        float temp = acc[bb] + bv;
        oHX[b*HN+h] = tanhf(xp[b*HN+h] + temp);
        oHY[b*HN+h] = tanhf(yp[b*HN+h] + temp);
    }
}

// ===========================================================================
extern "C" void kernel_launch(void* const* d_in, const int* in_sizes, int n_in,
                              void* d_out, int out_size, void* d_ws, size_t ws_size,
                              hipStream_t stream)
{
    const float* source = (const float*)d_in[0];
    const float* target = (const float*)d_in[1];
    const float* W      = (const float*)d_in[2]; // [2][256][256]
    const float* U      = (const float*)d_in[3]; // [2][512][256]
    const float* bias   = (const float*)d_in[4]; // [2][1][256]
    float* out = (float*)d_out;

    // ws layout: xp0 [1MB] | yp0 [1MB] | flags [48KB: L0, p1y, L1]
    const size_t need = 2u * 1024 * 1024 + 49152;
    if (d_ws != nullptr && ws_size >= need) {
        float* xp0 = (float*)d_ws;
        float* yp0 = xp0 + 32 * BH;
        int*   flg = (int*)(yp0 + 32 * BH);
        hipMemsetAsync(flg, 0, 3 * 4096 * sizeof(int), stream);
        proj0_kernel<<<dim3(64 * 4), dim3(256), 0, stream>>>(source, target, W, xp0, yp0);
        chain7_kernel<<<dim3(256), dim3(512), 0, stream>>>(
            W, U, bias, out, xp0, yp0, flg);
    } else {
        // Proven round-1 ladder (scratch aliased into out[1] region; safe
        // because proj1 runs only after ALL layer-0 diagonals).
        float* Xp0 = out + DSZ;
        float* Yp0 = Xp0 + SRCN * BH;
        proj0_kernel<<<dim3(64 * 4), dim3(256), 0, stream>>>(source, target, W, Xp0, Yp0);
        for (int t = 0; t < SRCN + TRGN - 1; ++t) {
            int nc = ncd(t);
            diag_kernel<<<dim3(nc * 4), dim3(256), 0, stream>>>(out, U, bias, Xp0, Yp0, 0, t);
        }
        proj1_kernel<<<dim3(1024 * 4), dim3(256), 0, stream>>>(out, W + HN * HN);
        for (int t = 0; t < SRCN + TRGN - 1; ++t) {
            int nc = ncd(t);
            diag_kernel<<<dim3(nc * 4), dim3(256), 0, stream>>>(out, U, bias, nullptr, nullptr, 1, t);
        }
    }
}